// Round 3
// baseline (96.803 us; speedup 1.0000x reference)
//
#include <hip/hip_runtime.h>

// IndRNN only-recurrent: h_t = relu(x_t + w * h_{t-1}), elementwise over [B,H],
// sequential over T. Pure HBM-streaming: 256 MiB in + 256 MiB out.
//
// R1 change (re-run after infra failure): VEC 4 -> 2. 65536 columns / 2 =
// 32768 threads = 256 blocks x 128 threads -> 2 waves/CU (was 1). Two
// independent h-chains + load queues per CU fill each other's issue bubbles
// (TLP on top of the DEPTH=16 ILP pipeline). 8 B/lane float2 loads stay in
// the coalescing sweet spot.

constexpr int T     = 1024;
constexpr int B     = 64;
constexpr int H     = 1024;
constexpr int N     = B * H;        // 65536 elements per timestep
constexpr int VEC   = 2;
constexpr int NT    = N / VEC;      // 32768 float2's per timestep
constexpr int BLOCK = 128;
constexpr int GRID  = NT / BLOCK;   // 256 blocks -> 1 per CU, 2 waves each
constexpr int DEPTH = 16;           // 2 waves x 64 lanes x 16 x 8B = 16 KiB/CU in flight

__global__ __launch_bounds__(BLOCK) void indrnn_kernel(
    const float2* __restrict__ x,    // [T][NT] as float2
    const float2* __restrict__ h0,   // [NT]
    const float*  __restrict__ w,    // [H]
    float2*       __restrict__ out)  // [T][NT]
{
    const int tid = blockIdx.x * BLOCK + threadIdx.x;   // 0..NT-1
    const int e   = tid * VEC;                          // first element index

    // Elements share the same batch row; weight index (e % H), 8B-aligned.
    const float2 wv = *reinterpret_cast<const float2*>(w + (e & (H - 1)));
    float2 h = h0[tid];

    const float2* xp = x + tid;
    float2*       op = out + tid;

    // Prefetch pipeline: buf[i] holds x_{t+i}. All indices compile-time
    // constants after unroll (registers, not scratch — rule #20).
    float2 buf[DEPTH];
#pragma unroll
    for (int i = 0; i < DEPTH; ++i) buf[i] = xp[i * NT];

    int t = 0;
    for (; t < T - DEPTH; t += DEPTH) {
#pragma unroll
        for (int i = 0; i < DEPTH; ++i) {
            const float2 xv = buf[i];
            buf[i] = xp[(t + DEPTH + i) * NT];   // issue next load early
            h.x = fmaxf(fmaf(h.x, wv.x, xv.x), 0.0f);
            h.y = fmaxf(fmaf(h.y, wv.y, xv.y), 0.0f);
            op[(t + i) * NT] = h;
        }
    }
    // Tail: last DEPTH timesteps, no prefetch.
#pragma unroll
    for (int i = 0; i < DEPTH; ++i) {
        const float2 xv = buf[i];
        h.x = fmaxf(fmaf(h.x, wv.x, xv.x), 0.0f);
        h.y = fmaxf(fmaf(h.y, wv.y, xv.y), 0.0f);
        op[(t + i) * NT] = h;
    }
}

extern "C" void kernel_launch(void* const* d_in, const int* in_sizes, int n_in,
                              void* d_out, int out_size, void* d_ws, size_t ws_size,
                              hipStream_t stream) {
    const float2* x  = (const float2*)d_in[0];  // input  [T,B,H] fp32
    const float2* h0 = (const float2*)d_in[1];  // h0     [B,H]   fp32
    const float*  w  = (const float*)d_in[2];   // weight [H]     fp32
    float2* out = (float2*)d_out;               // output [T,B,H] fp32

    indrnn_kernel<<<GRID, BLOCK, 0, stream>>>(x, h0, w, out);
}